// Round 3
// baseline (578.697 us; speedup 1.0000x reference)
//
#include <hip/hip_runtime.h>

// NeuralHashVoxel: multi-level hash-grid trilinear interpolation.
// N=1M points, L=6 levels, F=8 feats, T=524288 table rows, B=2^22 buckets.
// Round 2: full level unroll — all 48 idx gathers issued before any use
// (collapses 6 serial gather round-trips into 1).

static constexpr int      NPTS  = 1048576;
static constexpr int      LVLS  = 6;
static constexpr int      NF    = 8;
static constexpr int      TTAB  = 524288;
static constexpr unsigned BTAB  = 4194304u;          // 2^22 buckets per level
static constexpr unsigned BMASK = BTAB - 1u;         // mod B == & BMASK (B is pow2)
static constexpr unsigned P0 = 73856093u, P1 = 19349669u, P2 = 83492791u;

__global__ __launch_bounds__(256) void nhv_kernel(
    const float* __restrict__ qp,     // [N,3]
    const float* __restrict__ feat,   // [L,T,F]
    const int*   __restrict__ fidx,   // [L,B]  (-1 = empty)
    float*       __restrict__ out)    // [N,F]
{
    const int n = blockIdx.x * 256 + threadIdx.x;
    if (n >= NPTS) return;

    const float qx = qp[3 * n + 0];
    const float qy = qp[3 * n + 1];
    const float qz = qp[3 * n + 2];

    // Phase 1: all hashes + fractional coords (pure VALU, no memory).
    float    fx[LVLS], fy[LVLS], fz[LVLS];
    unsigned h[LVLS];
#pragma unroll
    for (int i = 0; i < LVLS; ++i) {
        // 1/res = 4,2,1,0.5,0.25,0.125 — exact powers of two, compile-time.
        const float inv = 4.0f / (float)(1 << i);
        const float sx = qx * inv, sy = qy * inv, sz = qz * inv;
        const float bx = floorf(sx), by = floorf(sy), bz = floorf(sz);
        fx[i] = sx - bx; fy[i] = sy - by; fz[i] = sz - bz;
        // base >= 0 (queries in [0,50)); uint32 wrap + mask == mod B (B=2^22 | 2^32)
        h[i] = (unsigned)(int)bx * P0 + (unsigned)(int)by * P1 + (unsigned)(int)bz * P2;
    }

    // Phase 2: issue ALL 48 idx gathers back-to-back (max MLP).
    int id[LVLS][8];
#pragma unroll
    for (int i = 0; i < LVLS; ++i) {
        const int* __restrict__ tab = fidx + (size_t)i * BTAB;
#pragma unroll
        for (int k = 0; k < 8; ++k) {
            unsigned key = h[i];
            if (k & 4) key += P0;
            if (k & 2) key += P1;
            if (k & 1) key += P2;
            id[i][k] = tab[key & BMASK];
        }
    }

    // Phase 3: per-level validity, coeffs, masked feature gather, accumulate.
    float acc[NF] = {0.f, 0.f, 0.f, 0.f, 0.f, 0.f, 0.f, 0.f};
#pragma unroll
    for (int i = 0; i < LVLS; ++i) {
        int mn = id[i][0];
#pragma unroll
        for (int k = 1; k < 8; ++k) mn = min(mn, id[i][k]);

        if (mn > -1) {
            const float wxv[2] = {1.0f - fx[i], fx[i]};
            const float wyv[2] = {1.0f - fy[i], fy[i]};
            const float wzv[2] = {1.0f - fz[i], fz[i]};
            const float* __restrict__ fb = feat + (size_t)i * (TTAB * NF);
#pragma unroll
            for (int k = 0; k < 8; ++k) {
                const float c = wxv[(k >> 2) & 1] * wyv[(k >> 1) & 1] * wzv[k & 1];
                const float4* p = (const float4*)(fb + (size_t)id[i][k] * NF);
                const float4 lo = p[0];
                const float4 hi = p[1];
                acc[0] += c * lo.x; acc[1] += c * lo.y;
                acc[2] += c * lo.z; acc[3] += c * lo.w;
                acc[4] += c * hi.x; acc[5] += c * hi.y;
                acc[6] += c * hi.z; acc[7] += c * hi.w;
            }
        }
    }

    float4* o = (float4*)(out + (size_t)n * NF);
    o[0] = make_float4(acc[0], acc[1], acc[2], acc[3]);
    o[1] = make_float4(acc[4], acc[5], acc[6], acc[7]);
}

extern "C" void kernel_launch(void* const* d_in, const int* in_sizes, int n_in,
                              void* d_out, int out_size, void* d_ws, size_t ws_size,
                              hipStream_t stream) {
    const float* qp   = (const float*)d_in[0];  // query_points [N,3] f32
    const float* feat = (const float*)d_in[1];  // features [L,T,F] f32
    const int*   fidx = (const int*)d_in[2];    // feature_indexs [L,B] int
    float*       out  = (float*)d_out;          // [N,F] f32

    dim3 grid(NPTS / 256), block(256);
    hipLaunchKernelGGL(nhv_kernel, grid, block, 0, stream, qp, feat, fidx, out);
}

// Round 4
// 382.655 us; speedup vs baseline: 1.5123x; 1.5123x over previous
//
#include <hip/hip_runtime.h>

// NeuralHashVoxel: multi-level hash-grid trilinear interpolation.
// Round 3: Morton-bin counting sort of query points (32K level-3-cell bins)
// -> spatial locality makes corner-key reuse L2-resident, cutting FETCH_SIZE.

static constexpr int      NPTS  = 1048576;
static constexpr int      LVLS  = 6;
static constexpr int      NF    = 8;
static constexpr int      TTAB  = 524288;
static constexpr unsigned BTAB  = 4194304u;          // 2^22 buckets per level
static constexpr unsigned BMASK = BTAB - 1u;         // mod B == & BMASK
static constexpr unsigned P0 = 73856093u, P1 = 19349669u, P2 = 83492791u;

static constexpr int    NBINS    = 32768;            // 2^15 Morton bins (cell = 2.0)
static constexpr size_t SORT_OFF = 131072;           // 128 KiB (ctr region), 16B-aligned
static constexpr size_t WS_NEEDED = SORT_OFF + (size_t)NPTS * 16;

// ---------------- shared per-point computation (round-2 structure) ----------
__device__ __forceinline__ void nhv_point(
    float qx, float qy, float qz,
    const float* __restrict__ feat, const int* __restrict__ fidx, float acc[NF])
{
    float    fx[LVLS], fy[LVLS], fz[LVLS];
    unsigned h[LVLS];
#pragma unroll
    for (int i = 0; i < LVLS; ++i) {
        const float inv = 4.0f / (float)(1 << i);    // exact pow2: q*inv == q/res
        const float sx = qx * inv, sy = qy * inv, sz = qz * inv;
        const float bx = floorf(sx), by = floorf(sy), bz = floorf(sz);
        fx[i] = sx - bx; fy[i] = sy - by; fz[i] = sz - bz;
        h[i] = (unsigned)(int)bx * P0 + (unsigned)(int)by * P1 + (unsigned)(int)bz * P2;
    }

    int id[LVLS][8];
#pragma unroll
    for (int i = 0; i < LVLS; ++i) {
        const int* __restrict__ tab = fidx + (size_t)i * BTAB;
#pragma unroll
        for (int k = 0; k < 8; ++k) {
            unsigned key = h[i];
            if (k & 4) key += P0;
            if (k & 2) key += P1;
            if (k & 1) key += P2;
            id[i][k] = tab[key & BMASK];
        }
    }

#pragma unroll
    for (int f = 0; f < NF; ++f) acc[f] = 0.0f;

#pragma unroll
    for (int i = 0; i < LVLS; ++i) {
        int mn = id[i][0];
#pragma unroll
        for (int k = 1; k < 8; ++k) mn = min(mn, id[i][k]);
        if (mn > -1) {
            const float wxv[2] = {1.0f - fx[i], fx[i]};
            const float wyv[2] = {1.0f - fy[i], fy[i]};
            const float wzv[2] = {1.0f - fz[i], fz[i]};
            const float* __restrict__ fb = feat + (size_t)i * (TTAB * NF);
#pragma unroll
            for (int k = 0; k < 8; ++k) {
                const float c = wxv[(k >> 2) & 1] * wyv[(k >> 1) & 1] * wzv[k & 1];
                const float4* p = (const float4*)(fb + (size_t)id[i][k] * NF);
                const float4 lo = p[0];
                const float4 hi = p[1];
                acc[0] += c * lo.x; acc[1] += c * lo.y;
                acc[2] += c * lo.z; acc[3] += c * lo.w;
                acc[4] += c * hi.x; acc[5] += c * hi.y;
                acc[6] += c * hi.z; acc[7] += c * hi.w;
            }
        }
    }
}

// ---------------- sorting passes ----------------
__device__ __forceinline__ unsigned expand5(unsigned v) {
    return (v & 1u) | ((v & 2u) << 2) | ((v & 4u) << 4) | ((v & 8u) << 6) | ((v & 16u) << 8);
}
__device__ __forceinline__ unsigned bin_of(float x, float y, float z) {
    // level-3 cell (size 2.0), coords in [0,25) -> 5 bits each, Morton interleave
    unsigned bx = (unsigned)(int)(x * 0.5f);
    unsigned by = (unsigned)(int)(y * 0.5f);
    unsigned bz = (unsigned)(int)(z * 0.5f);
    return expand5(bx) | (expand5(by) << 1) | (expand5(bz) << 2);
}

__global__ __launch_bounds__(256) void hist_k(const float* __restrict__ qp,
                                              unsigned* __restrict__ ctr) {
    const int n = blockIdx.x * 256 + threadIdx.x;
    if (n >= NPTS) return;
    atomicAdd(&ctr[bin_of(qp[3*n], qp[3*n+1], qp[3*n+2])], 1u);
}

// single block, 1024 threads: exclusive scan of 32768 counters in place
__global__ __launch_bounds__(1024) void scan_k(unsigned* __restrict__ ctr) {
    __shared__ unsigned part[1024];
    const int t = threadIdx.x;
    unsigned local[32];
    unsigned s = 0;
#pragma unroll
    for (int i = 0; i < 32; ++i) { local[i] = s; s += ctr[t * 32 + i]; }
    part[t] = s;
    __syncthreads();
    for (int d = 1; d < 1024; d <<= 1) {
        unsigned v = (t >= d) ? part[t - d] : 0u;
        __syncthreads();
        part[t] += v;
        __syncthreads();
    }
    const unsigned chunk_base = part[t] - s;   // exclusive base of this chunk
#pragma unroll
    for (int i = 0; i < 32; ++i) ctr[t * 32 + i] = chunk_base + local[i];
}

__global__ __launch_bounds__(256) void scatter_k(const float* __restrict__ qp,
                                                 unsigned* __restrict__ ctr,
                                                 float4* __restrict__ sorted) {
    const int n = blockIdx.x * 256 + threadIdx.x;
    if (n >= NPTS) return;
    const float x = qp[3*n], y = qp[3*n+1], z = qp[3*n+2];
    const unsigned pos = atomicAdd(&ctr[bin_of(x, y, z)], 1u);
    sorted[pos] = make_float4(x, y, z, __uint_as_float((unsigned)n));
}

// ---------------- main kernels ----------------
__global__ __launch_bounds__(256) void nhv_sorted_k(
    const float4* __restrict__ sp, const float* __restrict__ feat,
    const int* __restrict__ fidx, float* __restrict__ out)
{
    const int j = blockIdx.x * 256 + threadIdx.x;
    if (j >= NPTS) return;
    const float4 s = sp[j];
    float acc[NF];
    nhv_point(s.x, s.y, s.z, feat, fidx, acc);
    const unsigned n = __float_as_uint(s.w);
    float4* o = (float4*)(out + (size_t)n * NF);
    o[0] = make_float4(acc[0], acc[1], acc[2], acc[3]);
    o[1] = make_float4(acc[4], acc[5], acc[6], acc[7]);
}

__global__ __launch_bounds__(256) void nhv_direct_k(
    const float* __restrict__ qp, const float* __restrict__ feat,
    const int* __restrict__ fidx, float* __restrict__ out)
{
    const int n = blockIdx.x * 256 + threadIdx.x;
    if (n >= NPTS) return;
    float acc[NF];
    nhv_point(qp[3*n], qp[3*n+1], qp[3*n+2], feat, fidx, acc);
    float4* o = (float4*)(out + (size_t)n * NF);
    o[0] = make_float4(acc[0], acc[1], acc[2], acc[3]);
    o[1] = make_float4(acc[4], acc[5], acc[6], acc[7]);
}

extern "C" void kernel_launch(void* const* d_in, const int* in_sizes, int n_in,
                              void* d_out, int out_size, void* d_ws, size_t ws_size,
                              hipStream_t stream) {
    const float* qp   = (const float*)d_in[0];
    const float* feat = (const float*)d_in[1];
    const int*   fidx = (const int*)d_in[2];
    float*       out  = (float*)d_out;

    dim3 block(256), grid(NPTS / 256);

    if (ws_size >= WS_NEEDED) {
        unsigned* ctr    = (unsigned*)d_ws;
        float4*   sorted = (float4*)((char*)d_ws + SORT_OFF);
        hipMemsetAsync(ctr, 0, (size_t)NBINS * 4, stream);
        hipLaunchKernelGGL(hist_k,    grid, block, 0, stream, qp, ctr);
        hipLaunchKernelGGL(scan_k,    dim3(1), dim3(1024), 0, stream, ctr);
        hipLaunchKernelGGL(scatter_k, grid, block, 0, stream, qp, ctr, sorted);
        hipLaunchKernelGGL(nhv_sorted_k, grid, block, 0, stream, sorted, feat, fidx, out);
    } else {
        hipLaunchKernelGGL(nhv_direct_k, grid, block, 0, stream, qp, feat, fidx, out);
    }
}

// Round 5
// 210.940 us; speedup vs baseline: 2.7434x; 1.8140x over previous
//
#include <hip/hip_runtime.h>

// NeuralHashVoxel round 4: atomic-free block-radix counting sort (4096 Morton
// bins, LDS histograms + coalesced per-block prefix) + XCD-chunked main kernel.
// hist/binbase scratch lives in d_out (overwritten by main kernel afterwards).

static constexpr int      NPTS  = 1048576;
static constexpr int      LVLS  = 6;
static constexpr int      NF    = 8;
static constexpr int      TTAB  = 524288;
static constexpr unsigned BTAB  = 4194304u;          // 2^22 buckets per level
static constexpr unsigned BMASK = BTAB - 1u;
static constexpr unsigned P0 = 73856093u, P1 = 19349669u, P2 = 83492791u;

static constexpr int NBIN = 4096;        // 16^3 Morton bins, cell = 3.125
static constexpr int SB   = 256;         // sort blocks
static constexpr int PPB  = NPTS / SB;   // 4096 points per sort block
static constexpr int ITER = PPB / 256;   // 16 per thread

// ---------------- per-point computation (round-2 structure) ----------------
__device__ __forceinline__ void nhv_point(
    float qx, float qy, float qz,
    const float* __restrict__ feat, const int* __restrict__ fidx, float acc[NF])
{
    float    fx[LVLS], fy[LVLS], fz[LVLS];
    unsigned h[LVLS];
#pragma unroll
    for (int i = 0; i < LVLS; ++i) {
        const float inv = 4.0f / (float)(1 << i);    // exact pow2: q*inv == q/res
        const float sx = qx * inv, sy = qy * inv, sz = qz * inv;
        const float bx = floorf(sx), by = floorf(sy), bz = floorf(sz);
        fx[i] = sx - bx; fy[i] = sy - by; fz[i] = sz - bz;
        h[i] = (unsigned)(int)bx * P0 + (unsigned)(int)by * P1 + (unsigned)(int)bz * P2;
    }

    int id[LVLS][8];
#pragma unroll
    for (int i = 0; i < LVLS; ++i) {
        const int* __restrict__ tab = fidx + (size_t)i * BTAB;
#pragma unroll
        for (int k = 0; k < 8; ++k) {
            unsigned key = h[i];
            if (k & 4) key += P0;
            if (k & 2) key += P1;
            if (k & 1) key += P2;
            id[i][k] = tab[key & BMASK];
        }
    }

#pragma unroll
    for (int f = 0; f < NF; ++f) acc[f] = 0.0f;

#pragma unroll
    for (int i = 0; i < LVLS; ++i) {
        int mn = id[i][0];
#pragma unroll
        for (int k = 1; k < 8; ++k) mn = min(mn, id[i][k]);
        if (mn > -1) {
            const float wxv[2] = {1.0f - fx[i], fx[i]};
            const float wyv[2] = {1.0f - fy[i], fy[i]};
            const float wzv[2] = {1.0f - fz[i], fz[i]};
            const float* __restrict__ fb = feat + (size_t)i * (TTAB * NF);
#pragma unroll
            for (int k = 0; k < 8; ++k) {
                const float c = wxv[(k >> 2) & 1] * wyv[(k >> 1) & 1] * wzv[k & 1];
                const float4* p = (const float4*)(fb + (size_t)id[i][k] * NF);
                const float4 lo = p[0];
                const float4 hi = p[1];
                acc[0] += c * lo.x; acc[1] += c * lo.y;
                acc[2] += c * lo.z; acc[3] += c * lo.w;
                acc[4] += c * hi.x; acc[5] += c * hi.y;
                acc[6] += c * hi.z; acc[7] += c * hi.w;
            }
        }
    }
}

// ---------------- binning ----------------
__device__ __forceinline__ unsigned expand4(unsigned v) {
    return (v & 1u) | ((v & 2u) << 2) | ((v & 4u) << 4) | ((v & 8u) << 6);
}
__device__ __forceinline__ unsigned bin_of(float x, float y, float z) {
    // cell = 3.125 (=50/16): coords*0.32 in [0,16) exactly for x in [0,50)
    unsigned bx = min(15u, (unsigned)(int)(x * 0.32f));
    unsigned by = min(15u, (unsigned)(int)(y * 0.32f));
    unsigned bz = min(15u, (unsigned)(int)(z * 0.32f));
    return expand4(bx) | (expand4(by) << 1) | (expand4(bz) << 2);
}

// ---------------- sort passes (no global atomics) ----------------
__global__ __launch_bounds__(256) void hist_k(const float* __restrict__ qp,
                                              unsigned* __restrict__ hist) {
    __shared__ unsigned lh[NBIN];
    const int b = blockIdx.x, t = threadIdx.x;
    for (int i = t; i < NBIN; i += 256) lh[i] = 0u;
    __syncthreads();
    const int base = b * PPB;
#pragma unroll
    for (int i = 0; i < ITER; ++i) {
        const int p = base + i * 256 + t;
        atomicAdd(&lh[bin_of(qp[3*p], qp[3*p+1], qp[3*p+2])], 1u);
    }
    __syncthreads();
    for (int i = t; i < NBIN; i += 256) hist[(size_t)b * NBIN + i] = lh[i];
}

// per-bin exclusive prefix along blocks (in place) + per-bin totals
__global__ __launch_bounds__(256) void colscan_k(unsigned* __restrict__ hist,
                                                 unsigned* __restrict__ binbase) {
    const int bin = blockIdx.x * 256 + threadIdx.x;   // 16 blocks -> 4096 threads
    unsigned run = 0;
    for (int b = 0; b < SB; ++b) {
        const unsigned v = hist[(size_t)b * NBIN + bin];
        hist[(size_t)b * NBIN + bin] = run;
        run += v;
    }
    binbase[bin] = run;
}

// 1-block exclusive scan of the 4096 bin totals
__global__ __launch_bounds__(256) void binscan_k(unsigned* __restrict__ binbase) {
    __shared__ unsigned tot[256];
    const int t = threadIdx.x;
    unsigned v[16];
    unsigned s = 0;
#pragma unroll
    for (int i = 0; i < 16; ++i) { v[i] = s; s += binbase[t * 16 + i]; }
    tot[t] = s;
    __syncthreads();
    for (int d = 1; d < 256; d <<= 1) {
        const unsigned x = (t >= d) ? tot[t - d] : 0u;
        __syncthreads();
        tot[t] += x;
        __syncthreads();
    }
    const unsigned cb = tot[t] - s;
#pragma unroll
    for (int i = 0; i < 16; ++i) binbase[t * 16 + i] = cb + v[i];
}

__global__ __launch_bounds__(256) void scatter_k(const float* __restrict__ qp,
                                                 const unsigned* __restrict__ hist,
                                                 const unsigned* __restrict__ binbase,
                                                 float4* __restrict__ sorted) {
    __shared__ unsigned cur[NBIN];
    const int b = blockIdx.x, t = threadIdx.x;
    for (int i = t; i < NBIN; i += 256)
        cur[i] = binbase[i] + hist[(size_t)b * NBIN + i];
    __syncthreads();
    const int base = b * PPB;
#pragma unroll
    for (int i = 0; i < ITER; ++i) {
        const int p = base + i * 256 + t;
        const float x = qp[3*p], y = qp[3*p+1], z = qp[3*p+2];
        const unsigned slot = atomicAdd(&cur[bin_of(x, y, z)], 1u);
        sorted[slot] = make_float4(x, y, z, __uint_as_float((unsigned)p));
    }
}

// ---------------- main kernels ----------------
__global__ __launch_bounds__(256) void nhv_sorted_k(
    const float4* __restrict__ sp, const float* __restrict__ feat,
    const int* __restrict__ fidx, float* __restrict__ out)
{
    // XCD-chunked swizzle: 4096 blocks % 8 == 0 -> bijective; each XCD gets a
    // contiguous Morton (spatial) slab so its private L2 holds that slab's keys.
    const int nwg = NPTS / 256;
    const int bid = blockIdx.x;
    const int swz = (bid & 7) * (nwg >> 3) + (bid >> 3);
    const int j   = swz * 256 + (int)threadIdx.x;

    const float4 s = sp[j];
    float acc[NF];
    nhv_point(s.x, s.y, s.z, feat, fidx, acc);
    const unsigned n = __float_as_uint(s.w);
    float4* o = (float4*)(out + (size_t)n * NF);
    o[0] = make_float4(acc[0], acc[1], acc[2], acc[3]);
    o[1] = make_float4(acc[4], acc[5], acc[6], acc[7]);
}

__global__ __launch_bounds__(256) void nhv_direct_k(
    const float* __restrict__ qp, const float* __restrict__ feat,
    const int* __restrict__ fidx, float* __restrict__ out)
{
    const int n = blockIdx.x * 256 + threadIdx.x;
    if (n >= NPTS) return;
    float acc[NF];
    nhv_point(qp[3*n], qp[3*n+1], qp[3*n+2], feat, fidx, acc);
    float4* o = (float4*)(out + (size_t)n * NF);
    o[0] = make_float4(acc[0], acc[1], acc[2], acc[3]);
    o[1] = make_float4(acc[4], acc[5], acc[6], acc[7]);
}

extern "C" void kernel_launch(void* const* d_in, const int* in_sizes, int n_in,
                              void* d_out, int out_size, void* d_ws, size_t ws_size,
                              hipStream_t stream) {
    const float* qp   = (const float*)d_in[0];
    const float* feat = (const float*)d_in[1];
    const int*   fidx = (const int*)d_in[2];
    float*       out  = (float*)d_out;

    const size_t ws_needed = (size_t)NPTS * 16;       // sorted buffer only

    if (ws_size >= ws_needed) {
        // hist (4 MB) + binbase (16 KB) live in d_out; the main kernel fully
        // overwrites d_out afterwards (same stream, ordered) -> deterministic.
        unsigned* hist    = (unsigned*)d_out;
        unsigned* binbase = hist + (size_t)SB * NBIN;
        float4*   sorted  = (float4*)d_ws;

        hipLaunchKernelGGL(hist_k,    dim3(SB),  dim3(256), 0, stream, qp, hist);
        hipLaunchKernelGGL(colscan_k, dim3(16),  dim3(256), 0, stream, hist, binbase);
        hipLaunchKernelGGL(binscan_k, dim3(1),   dim3(256), 0, stream, binbase);
        hipLaunchKernelGGL(scatter_k, dim3(SB),  dim3(256), 0, stream, qp, hist, binbase, sorted);
        hipLaunchKernelGGL(nhv_sorted_k, dim3(NPTS/256), dim3(256), 0, stream,
                           sorted, feat, fidx, out);
    } else {
        hipLaunchKernelGGL(nhv_direct_k, dim3(NPTS/256), dim3(256), 0, stream,
                           qp, feat, fidx, out);
    }
}